// Round 11
// baseline (186.902 us; speedup 1.0000x reference)
//
#include <hip/hip_runtime.h>
#include <hip/hip_bf16.h>

#define B_N 4096
#define T_N 64
#define D_N 256
#define H_N 128
#define K_N 12

typedef __attribute__((ext_vector_type(8))) short short8;
typedef __attribute__((ext_vector_type(4))) float f32x4;

static __device__ __forceinline__ unsigned bf16_rne(float x) {
  unsigned u = __float_as_uint(x);
  return (u + 0x7fffu + ((u >> 16) & 1u)) >> 16;
}
static __device__ __forceinline__ unsigned pk2(float a, float b) {
  return bf16_rne(a) | (bf16_rne(b) << 16);
}
static __device__ __forceinline__ float lo16(unsigned u) { return __uint_as_float(u << 16); }
static __device__ __forceinline__ float hi16(unsigned u) { return __uint_as_float(u & 0xffff0000u); }

// ---------------------------------------------------------------------------
// prep_wa: pack w_atom into bf16 B-fragments (verified layout from R7).
// ---------------------------------------------------------------------------
__global__ void prep_wa(const float* __restrict__ w_atom, unsigned* __restrict__ wa_frag) {
  const int tid = blockIdx.x * 64 + threadIdx.x;   // 512 threads
  const int s = tid >> 6, l = tid & 63;
  const int k = l & 15, h = l >> 4, d0 = s * 32 + h * 8;
  unsigned o[4];
#pragma unroll
  for (int j = 0; j < 4; ++j) {
    const float a = (k < K_N) ? w_atom[k * D_N + d0 + 2 * j]     : 0.f;
    const float b = (k < K_N) ? w_atom[k * D_N + d0 + 2 * j + 1] : 0.f;
    o[j] = pk2(a, b);
  }
  *(uint4*)(wa_frag + (size_t)tid * 4) = make_uint4(o[0], o[1], o[2], o[3]);
}

// ---------------------------------------------------------------------------
// prep_w: pack layer weight W[k][D][H_N] (D=32*S) into bf16 B-fragments.
// ---------------------------------------------------------------------------
__global__ void prep_w(const float* __restrict__ W, unsigned* __restrict__ out, int S) {
  const int id = blockIdx.x * 256 + threadIdx.x;
  const int total = K_N * 8 * S * 64;
  if (id >= total) return;
  const int lane = id & 63;
  const int s  = (id >> 6) % S;
  const int nt = ((id >> 6) / S) & 7;
  const int kk = id / (64 * S * 8);
  const int n  = nt * 16 + (lane & 15);
  const int d0 = 32 * s + 8 * (lane >> 4);
  const int D  = 32 * S;
  unsigned o[4];
#pragma unroll
  for (int j = 0; j < 4; ++j) {
    const float a = W[(size_t)kk * D * H_N + (d0 + 2 * j) * H_N + n];
    const float b = W[(size_t)kk * D * H_N + (d0 + 2 * j + 1) * H_N + n];
    o[j] = pk2(a, b);
  }
  *(uint4*)(out + (size_t)id * 4) = make_uint4(o[0], o[1], o[2], o[3]);
}

// ---------------------------------------------------------------------------
// K1 producer/consumer: 512 threads, waves 0-3 produce (stream feats ->
// double-buffered bf16 LDS tile), waves 4-7 consume (p1 MFMA sigmoid, p2 mol).
// Raw s_barriers with lgkmcnt-only drains: producer global loads stay in
// flight across barriers -> HBM streams under consumer compute.
// Per block: NB=8 consecutive b's.  Grid 512 -> 2 blocks/CU (68.6 KB LDS).
// Barrier schedule per iter: [prod issue loads b+1 | cons p1+p1.5] MID
// [prod cvt+write tile^1 | cons p2+stores] END.
// ---------------------------------------------------------------------------
__global__ __launch_bounds__(512, 4) void k1_mol(
    const int* __restrict__ dx, const float* __restrict__ feats,
    const unsigned* __restrict__ wa_frag, const float* __restrict__ b_atom,
    float* __restrict__ out_atom, unsigned* __restrict__ molb)
{
  __shared__ unsigned tile[2][64 * 128];   // 2 x 32 KB bf16, 16B-granule swizzle
  __shared__ float wv32[K_N * 64];

  const int tid  = threadIdx.x;
  const int lane = tid & 63;
  const int w    = tid >> 6;
  const int b0   = blockIdx.x * 8;

  if (w < 4) {
    // ======================= PRODUCER waves ================================
    const int pw = w;
    const size_t rowbase = (size_t)(16 * pw) * 256 + 4 * lane;
    float4 r[16];

    // prologue: stage b0 into tile[0]
    {
      const float* fg = feats + ((size_t)b0 * 65 + 1) * 256 + rowbase;
#pragma unroll
      for (int i = 0; i < 16; ++i) r[i] = *(const float4*)(fg + (size_t)i * 256);
#pragma unroll
      for (int i = 0; i < 16; ++i) {
        const unsigned off = (16 * pw + i) * 128 + (((lane >> 1) ^ i) << 2) + (lane & 1) * 2;
        *(uint2*)&tile[0][off] = make_uint2(pk2(r[i].x, r[i].y), pk2(r[i].z, r[i].w));
      }
      asm volatile("s_waitcnt lgkmcnt(0)" ::: "memory");
      __builtin_amdgcn_s_barrier();           // prologue barrier
    }

    for (int ib = 0; ib < 8; ++ib) {
      if (ib + 1 < 8) {   // issue next tile's loads; they fly across MID
        const float* fg = feats + ((size_t)(b0 + ib + 1) * 65 + 1) * 256 + rowbase;
#pragma unroll
        for (int i = 0; i < 16; ++i) r[i] = *(const float4*)(fg + (size_t)i * 256);
      }
      __builtin_amdgcn_s_barrier();           // MID (consumers finished p1.5)
      if (ib + 1 < 8) {
        unsigned* dst = &tile[(ib + 1) & 1][0];
#pragma unroll
        for (int i = 0; i < 16; ++i) {
          const unsigned off = (16 * pw + i) * 128 + (((lane >> 1) ^ i) << 2) + (lane & 1) * 2;
          *(uint2*)&dst[off] = make_uint2(pk2(r[i].x, r[i].y), pk2(r[i].z, r[i].w));
        }
      }
      asm volatile("s_waitcnt lgkmcnt(0)" ::: "memory");
      __builtin_amdgcn_s_barrier();           // END (tile^1 ready)
    }
  } else {
    // ======================= CONSUMER waves ================================
    const int cw = w - 4;
    const int k = lane & 15, h = lane >> 4;
    short8 bfr[8];
    {
      const short8* wf8 = (const short8*)wa_frag;
#pragma unroll
      for (int s = 0; s < 8; ++s) bfr[s] = wf8[s * 64 + lane];
    }
    const float ba = (k < K_N) ? b_atom[k] : 0.f;
    __builtin_amdgcn_s_barrier();             // prologue barrier

    for (int ib = 0; ib < 8; ++ib) {
      const int b = b0 + ib;
      const unsigned* tl = &tile[ib & 1][0];
      const int4 dvv = *(const int4*)(dx + b * T_N + 16 * cw + 4 * h);

      // ---- phase 1: C[t,k] via 8 mfma steps -------------------------------
      f32x4 cacc = {0.f, 0.f, 0.f, 0.f};
#pragma unroll
      for (int s = 0; s < 8; ++s) {
        const unsigned off = (16 * cw + k) * 128 + (((4 * s + h) ^ k) << 2);
        const short8 af = *(const short8*)&tl[off];
        cacc = __builtin_amdgcn_mfma_f32_16x16x32_bf16(af, bfr[s], cacc, 0, 0, 0);
      }
      // ---- phase 1.5: wv = valid * sigmoid(C + ba) -> wv32 ----------------
#pragma unroll
      for (int rr = 0; rr < 4; ++rr) {
        const float valid = (((const int*)&dvv)[rr] != 0) ? 1.f : 0.f;
        const float wvv = valid / (1.f + __expf(-(cacc[rr] + ba)));
        if (k < K_N) wv32[k * 64 + 16 * cw + 4 * h + rr] = wvv;
      }
      asm volatile("s_waitcnt lgkmcnt(0)" ::: "memory");
      __builtin_amdgcn_s_barrier();           // MID (wv32 ready)

      // ---- phase 2: mol[k][d] over all t; wave owns k=3cw..3cw+2 ----------
      const int kb = cw * 3;
      float4 m0 = make_float4(0.f, 0.f, 0.f, 0.f), m1 = m0, m2 = m0;
#pragma unroll
      for (int tc = 0; tc < 16; ++tc) {
        const float4 wv0 = *(const float4*)&wv32[(kb + 0) * 64 + (tc << 2)];
        const float4 wv1 = *(const float4*)&wv32[(kb + 1) * 64 + (tc << 2)];
        const float4 wv2 = *(const float4*)&wv32[(kb + 2) * 64 + (tc << 2)];
        const float w0a[4] = {wv0.x, wv0.y, wv0.z, wv0.w};
        const float w1a[4] = {wv1.x, wv1.y, wv1.z, wv1.w};
        const float w2a[4] = {wv2.x, wv2.y, wv2.z, wv2.w};
#pragma unroll
        for (int j = 0; j < 4; ++j) {
          const int t = (tc << 2) + j;
          const unsigned off = t * 128 + (((lane >> 1) ^ (t & 15)) << 2) + (lane & 1) * 2;
          const uint2 pw2 = *(const uint2*)&tl[off];
          const float f0 = lo16(pw2.x), f1 = hi16(pw2.x);
          const float f2 = lo16(pw2.y), f3 = hi16(pw2.y);
          m0.x = fmaf(w0a[j], f0, m0.x); m0.y = fmaf(w0a[j], f1, m0.y);
          m0.z = fmaf(w0a[j], f2, m0.z); m0.w = fmaf(w0a[j], f3, m0.w);
          m1.x = fmaf(w1a[j], f0, m1.x); m1.y = fmaf(w1a[j], f1, m1.y);
          m1.z = fmaf(w1a[j], f2, m1.z); m1.w = fmaf(w1a[j], f3, m1.w);
          m2.x = fmaf(w2a[j], f0, m2.x); m2.y = fmaf(w2a[j], f1, m2.y);
          m2.z = fmaf(w2a[j], f2, m2.z); m2.w = fmaf(w2a[j], f3, m2.w);
        }
      }
      unsigned* mpb = molb + ((size_t)kb * B_N + b) * 128 + (lane << 1);
      *(uint2*)(mpb)                         = make_uint2(pk2(m0.x, m0.y), pk2(m0.z, m0.w));
      *(uint2*)(mpb + (size_t)B_N * 128)     = make_uint2(pk2(m1.x, m1.y), pk2(m1.z, m1.w));
      *(uint2*)(mpb + (size_t)2 * B_N * 128) = make_uint2(pk2(m2.x, m2.y), pk2(m2.z, m2.w));

      const int ctid = tid - 256;
      if (ctid < 192) {
        const float4 v = *(const float4*)&wv32[ctid * 4];
        const int kk = ctid >> 4, t0 = (ctid & 15) * 4;
        *(float4*)&out_atom[((size_t)kk * B_N + b) * T_N + t0] = v;
      }
      __builtin_amdgcn_s_barrier();           // END
    }
  }
}

// ---------------------------------------------------------------------------
// MFMA GEMM layer (unchanged from R9).
// ---------------------------------------------------------------------------
template <int S, bool AFFINE>
__global__ __launch_bounds__(256) void gemm_mfma(
    const unsigned* __restrict__ Abf, const unsigned* __restrict__ wpack,
    const float* __restrict__ bias, const float* __restrict__ alpha,
    const float* __restrict__ beta, unsigned short* __restrict__ Hout,
    float* __restrict__ ssum, float* __restrict__ ssq)
{
  __shared__ unsigned tile[64 * S * 16];
  __shared__ float redS[4][8][16];
  __shared__ float redQ[4][8][16];

  const int k   = blockIdx.y;
  const int b0  = blockIdx.x << 6;
  const int tid = threadIdx.x;
  const int lane = tid & 63;
  const int wv  = tid >> 6;
  const int ln15 = lane & 15;
  const int hq   = lane >> 4;

  {
    const int row = tid >> 2, q = tid & 3;
    const uint4* Ar = (const uint4*)Abf + ((size_t)k * B_N + b0 + row) * (S * 4) + q * S;
#pragma unroll
    for (int gi = 0; gi < S; ++gi) {
      const int g = q * S + gi;
      uint4 u = Ar[gi];
      if (AFFINE) {
        const float4 al0 = *(const float4*)(alpha + k * H_N + g * 8);
        const float4 al1 = *(const float4*)(alpha + k * H_N + g * 8 + 4);
        const float4 bt0 = *(const float4*)(beta  + k * H_N + g * 8);
        const float4 bt1 = *(const float4*)(beta  + k * H_N + g * 8 + 4);
        u.x = pk2(fmaf(lo16(u.x), al0.x, bt0.x), fmaf(hi16(u.x), al0.y, bt0.y));
        u.y = pk2(fmaf(lo16(u.y), al0.z, bt0.z), fmaf(hi16(u.y), al0.w, bt0.w));
        u.z = pk2(fmaf(lo16(u.z), al1.x, bt1.x), fmaf(hi16(u.z), al1.y, bt1.y));
        u.w = pk2(fmaf(lo16(u.w), al1.z, bt1.z), fmaf(hi16(u.w), al1.w, bt1.w));
      }
      *(uint4*)&tile[row * (S * 16) + ((g ^ (row & 15)) << 2)] = u;
    }
  }
  __syncthreads();

  const short8* wp8 = (const short8*)wpack + (size_t)k * 8 * S * 64 + lane;
  f32x4 acc[8];
#pragma unroll
  for (int nt = 0; nt < 8; ++nt) acc[nt] = (f32x4){0.f, 0.f, 0.f, 0.f};

  short8 bs0[8], bs1[8];
#pragma unroll
  for (int nt = 0; nt < 8; ++nt) bs0[nt] = wp8[(nt * S) * 64];
#pragma unroll
  for (int s = 0; s < S; ++s) {
    if (s + 1 < S) {
#pragma unroll
      for (int nt = 0; nt < 8; ++nt) {
        if (s & 1) bs0[nt] = wp8[(nt * S + s + 1) * 64];
        else       bs1[nt] = wp8[(nt * S + s + 1) * 64];
      }
    }
    const int arow = (wv << 4) + ln15;
    const unsigned aoff = arow * (S * 16) + (((4 * s + hq) ^ ln15) << 2);
    const short8 af = *(const short8*)&tile[aoff];
#pragma unroll
    for (int nt = 0; nt < 8; ++nt) {
      const short8 bf = (s & 1) ? bs1[nt] : bs0[nt];
      acc[nt] = __builtin_amdgcn_mfma_f32_16x16x32_bf16(af, bf, acc[nt], 0, 0, 0);
    }
  }

#pragma unroll
  for (int nt = 0; nt < 8; ++nt) {
    const int col = nt * 16 + ln15;
    const float bv = bias[k * H_N + col];
    float cs = 0.f, cq = 0.f;
#pragma unroll
    for (int r = 0; r < 4; ++r) {
      const float o = fmaxf(acc[nt][r] + bv, 0.f);
      cs += o; cq = fmaf(o, o, cq);
      const int row = b0 + (wv << 4) + (hq << 2) + r;
      Hout[((size_t)k * B_N + row) * H_N + col] = (unsigned short)bf16_rne(o);
    }
    cs += __shfl_xor(cs, 16); cs += __shfl_xor(cs, 32);
    cq += __shfl_xor(cq, 16); cq += __shfl_xor(cq, 32);
    if (lane < 16) { redS[wv][nt][ln15] = cs; redQ[wv][nt][ln15] = cq; }
  }
  __syncthreads();
  if (tid < 128) {
    const int nt = tid >> 4, c = tid & 15;
    float s = 0.f, q = 0.f;
#pragma unroll
    for (int i = 0; i < 4; ++i) { s += redS[i][nt][c]; q += redQ[i][nt][c]; }
    atomicAdd(&ssum[k * H_N + nt * 16 + c], s);
    atomicAdd(&ssq[k * H_N + nt * 16 + c], q);
  }
}

// stats -> alpha/beta
__global__ void bn_coef(const float* __restrict__ ssum, const float* __restrict__ ssq,
                        const float* __restrict__ g, const float* __restrict__ be,
                        float* __restrict__ alpha, float* __restrict__ beta)
{
  const int i = blockIdx.x * 256 + threadIdx.x;
  if (i >= K_N * H_N) return;
  const float inv_n = 1.f / (float)B_N;
  const float m = ssum[i] * inv_n;
  float v = fmaf(ssq[i], inv_n, -m * m);
  v = fmaxf(v, 0.f);
  const float a = g[i] * rsqrtf(v + 1e-5f);
  alpha[i] = a;
  beta[i]  = fmaf(-m, a, be[i]);
}

// final: pred[b,k] = dot(h3*al+bt, Wout) + bout  (one wave per (b,k); h3 bf16)
__global__ __launch_bounds__(256) void k_pred(
    const unsigned* __restrict__ h3, const float* __restrict__ alpha,
    const float* __restrict__ beta, const float* __restrict__ Wout,
    const float* __restrict__ bout, float* __restrict__ out)
{
  const int lane = threadIdx.x & 63;
  const int wv   = threadIdx.x >> 6;
  const int pair = blockIdx.x * 4 + wv;
  const int b = pair / K_N, k = pair - b * K_N;
  const unsigned xp = h3[((size_t)k * B_N + b) * 64 + lane];
  const float2 al = *(const float2*)(alpha + k * H_N + (lane << 1));
  const float2 be = *(const float2*)(beta  + k * H_N + (lane << 1));
  const float2 wo = *(const float2*)(Wout  + k * H_N + (lane << 1));
  float s = fmaf(lo16(xp), al.x, be.x) * wo.x + fmaf(hi16(xp), al.y, be.y) * wo.y;
#pragma unroll
  for (int off = 32; off; off >>= 1) s += __shfl_down(s, off);
  if (lane == 0) out[pair] = s + bout[k];
}

extern "C" void kernel_launch(void* const* d_in, const int* in_sizes, int n_in,
                              void* d_out, int out_size, void* d_ws, size_t ws_size,
                              hipStream_t stream)
{
  (void)in_sizes; (void)n_in; (void)out_size; (void)ws_size;
  const int*   dx     = (const int*)d_in[0];
  const float* feats  = (const float*)d_in[1];
  const float* w_atom = (const float*)d_in[2];
  const float* b_atom = (const float*)d_in[3];
  const float* W1 = (const float*)d_in[4];
  const float* b1 = (const float*)d_in[5];
  const float* g1 = (const float*)d_in[6];
  const float* be1 = (const float*)d_in[7];
  const float* W2 = (const float*)d_in[8];
  const float* b2 = (const float*)d_in[9];
  const float* g2 = (const float*)d_in[10];
  const float* be2 = (const float*)d_in[11];
  const float* W3 = (const float*)d_in[12];
  const float* b3 = (const float*)d_in[13];
  const float* g3 = (const float*)d_in[14];
  const float* be3 = (const float*)d_in[15];
  const float* Wout = (const float*)d_in[16];
  const float* bout = (const float*)d_in[17];

  float* out      = (float*)d_out;
  float* pred_out = out;                       // (B, K)
  float* atom_out = out + (size_t)B_N * K_N;   // (K, B, T)

  // ---- workspace layout (bytes) ----
  char* wsb = (char*)d_ws;
  unsigned*       molb = (unsigned*)wsb;                       // bf16 K*B*D
  unsigned short* h1   = (unsigned short*)(wsb + 25165824);
  unsigned short* h2   = (unsigned short*)(wsb + 37748736);
  unsigned short* h3   = (unsigned short*)(wsb + 50331648);
  float* st = (float*)(wsb + 62914560);
  float* s1 = st,        *q1 = st + 1536;
  float* s2 = st + 3072, *q2 = st + 4608;
  float* s3 = st + 6144, *q3 = st + 7680;
  float* ab = st + 9216;
  float* al1 = ab,        *bt1 = ab + 1536;
  float* al2 = ab + 3072, *bt2 = ab + 4608;
  float* al3 = ab + 6144, *bt3 = ab + 7680;
  unsigned* wa_frag = (unsigned*)(ab + 9216);
  unsigned* w1p = wa_frag + 2048;
  unsigned* w2p = w1p + 196608;
  unsigned* w3p = w2p + 98304;

  hipMemsetAsync(st, 0, 6 * 1536 * sizeof(float), stream);

  prep_wa<<<8, 64, 0, stream>>>(w_atom, wa_frag);
  prep_w<<<(K_N * 8 * 8 * 64 + 255) / 256, 256, 0, stream>>>(W1, w1p, 8);
  prep_w<<<(K_N * 8 * 4 * 64 + 255) / 256, 256, 0, stream>>>(W2, w2p, 4);
  prep_w<<<(K_N * 8 * 4 * 64 + 255) / 256, 256, 0, stream>>>(W3, w3p, 4);

  k1_mol<<<B_N / 8, 512, 0, stream>>>(dx, feats, wa_frag, b_atom, atom_out, molb);

  gemm_mfma<8, false><<<dim3(64, 12), 256, 0, stream>>>(
      molb, w1p, b1, nullptr, nullptr, h1, s1, q1);
  bn_coef<<<6, 256, 0, stream>>>(s1, q1, g1, be1, al1, bt1);
  gemm_mfma<4, true><<<dim3(64, 12), 256, 0, stream>>>(
      (const unsigned*)h1, w2p, b2, al1, bt1, h2, s2, q2);
  bn_coef<<<6, 256, 0, stream>>>(s2, q2, g2, be2, al2, bt2);
  gemm_mfma<4, true><<<dim3(64, 12), 256, 0, stream>>>(
      (const unsigned*)h2, w3p, b3, al2, bt2, h3, s3, q3);
  bn_coef<<<6, 256, 0, stream>>>(s3, q3, g3, be3, al3, bt3);
  k_pred<<<B_N * K_N / 4, 256, 0, stream>>>(
      (const unsigned*)h3, al3, bt3, Wout, bout, pred_out);
}

// Round 12
// 145.442 us; speedup vs baseline: 1.2851x; 1.2851x over previous
//
#include <hip/hip_runtime.h>
#include <hip/hip_bf16.h>

#define B_N 4096
#define T_N 64
#define D_N 256
#define H_N 128
#define K_N 12

typedef __attribute__((ext_vector_type(8))) short short8;
typedef __attribute__((ext_vector_type(4))) float f32x4;

static __device__ __forceinline__ unsigned bf16_rne(float x) {
  unsigned u = __float_as_uint(x);
  return (u + 0x7fffu + ((u >> 16) & 1u)) >> 16;
}
static __device__ __forceinline__ unsigned pk2(float a, float b) {
  return bf16_rne(a) | (bf16_rne(b) << 16);
}
static __device__ __forceinline__ float lo16(unsigned u) { return __uint_as_float(u << 16); }
static __device__ __forceinline__ float hi16(unsigned u) { return __uint_as_float(u & 0xffff0000u); }

// ---------------------------------------------------------------------------
// prep_wa: pack w_atom into bf16 B-fragments (verified layout from R7).
// ---------------------------------------------------------------------------
__global__ void prep_wa(const float* __restrict__ w_atom, unsigned* __restrict__ wa_frag) {
  const int tid = blockIdx.x * 64 + threadIdx.x;   // 512 threads
  const int s = tid >> 6, l = tid & 63;
  const int k = l & 15, h = l >> 4, d0 = s * 32 + h * 8;
  unsigned o[4];
#pragma unroll
  for (int j = 0; j < 4; ++j) {
    const float a = (k < K_N) ? w_atom[k * D_N + d0 + 2 * j]     : 0.f;
    const float b = (k < K_N) ? w_atom[k * D_N + d0 + 2 * j + 1] : 0.f;
    o[j] = pk2(a, b);
  }
  *(uint4*)(wa_frag + (size_t)tid * 4) = make_uint4(o[0], o[1], o[2], o[3]);
}

// ---------------------------------------------------------------------------
// prep_w: pack layer weight W[k][D][H_N] (D=32*S) into bf16 B-fragments.
// ---------------------------------------------------------------------------
__global__ void prep_w(const float* __restrict__ W, unsigned* __restrict__ out, int S) {
  const int id = blockIdx.x * 256 + threadIdx.x;
  const int total = K_N * 8 * S * 64;
  if (id >= total) return;
  const int lane = id & 63;
  const int s  = (id >> 6) % S;
  const int nt = ((id >> 6) / S) & 7;
  const int kk = id / (64 * S * 8);
  const int n  = nt * 16 + (lane & 15);
  const int d0 = 32 * s + 8 * (lane >> 4);
  const int D  = 32 * S;
  unsigned o[4];
#pragma unroll
  for (int j = 0; j < 4; ++j) {
    const float a = W[(size_t)kk * D * H_N + (d0 + 2 * j) * H_N + n];
    const float b = W[(size_t)kk * D * H_N + (d0 + 2 * j + 1) * H_N + n];
    o[j] = pk2(a, b);
  }
  *(uint4*)(out + (size_t)id * 4) = make_uint4(o[0], o[1], o[2], o[3]);
}

// ---------------------------------------------------------------------------
// K1 (R9 structure, first barrier REMOVED): one block per b, 4 waves.
// Key dataflow fact: wave w stages rows 16w..16w+15 and phase-1 reads ONLY
// those rows -> stage/p1 need no cross-wave sync (same-wave lgkmcnt ordering
// suffices).  The single barrier sits between p1.5 (wv32 writes) and p2
// (full-tile + wv32 reads).  This breaks the block-wide stage convoy: each
// of the 16 waves/CU streams HBM and computes independently until p2.
// dx loaded per-wave as int4 (dxv LDS removed).  35.3KB LDS -> 4 blocks/CU.
// ---------------------------------------------------------------------------
__global__ __launch_bounds__(256, 4) void k1_mol(
    const int* __restrict__ dx, const float* __restrict__ feats,
    const unsigned* __restrict__ wa_frag, const float* __restrict__ b_atom,
    float* __restrict__ out_atom, unsigned* __restrict__ molb)
{
  __shared__ unsigned tile[64 * 128];   // 32 KB bf16 tile, 16B-granule swizzle
  __shared__ float wv32[K_N * 64];

  const int tid  = threadIdx.x;
  const int lane = tid & 63;
  const int w    = tid >> 6;
  const int b    = blockIdx.x;
  const int k    = lane & 15;
  const int h    = lane >> 4;

  short8 bfr[8];
  {
    const short8* wf8 = (const short8*)wa_frag;
#pragma unroll
    for (int s = 0; s < 8; ++s) bfr[s] = wf8[s * 64 + lane];
  }
  const float ba = (k < K_N) ? b_atom[k] : 0.f;
  const int4 dvv = *(const int4*)(dx + b * T_N + 16 * w + 4 * h);

  // ---- stage own rows: no cross-wave dependency ---------------------------
  const float* fg = feats + ((size_t)b * 65 + 1) * 256;
#pragma unroll
  for (int c = 0; c < 4; ++c) {
    float4 v[4];
#pragma unroll
    for (int i = 0; i < 4; ++i)
      v[i] = *(const float4*)(fg + (size_t)(16 * w + 4 * c + i) * 256 + 4 * lane);
#pragma unroll
    for (int i = 0; i < 4; ++i) {
      const int tl = 4 * c + i;
      const int t  = 16 * w + tl;
      const unsigned off = t * 128 + (((lane >> 1) ^ tl) << 2) + (lane & 1) * 2;
      *(uint2*)&tile[off] = make_uint2(pk2(v[i].x, v[i].y), pk2(v[i].z, v[i].w));
    }
  }
  // NO barrier: phase 1 reads only this wave's rows (lgkmcnt ordering).

  // ---- phase 1: C[t,k] via 8 mfma steps -----------------------------------
  f32x4 cacc = {0.f, 0.f, 0.f, 0.f};
#pragma unroll
  for (int s = 0; s < 8; ++s) {
    const unsigned off = (16 * w + k) * 128 + (((4 * s + h) ^ k) << 2);
    const short8 afrag = *(const short8*)&tile[off];
    cacc = __builtin_amdgcn_mfma_f32_16x16x32_bf16(afrag, bfr[s], cacc, 0, 0, 0);
  }

  // ---- phase 1.5: wv = valid * sigmoid(C + ba) -> wv32 --------------------
#pragma unroll
  for (int r = 0; r < 4; ++r) {
    const float valid = (((const int*)&dvv)[r] != 0) ? 1.f : 0.f;
    const float wv = valid / (1.f + __expf(-(cacc[r] + ba)));
    if (k < K_N) wv32[k * 64 + 16 * w + 4 * h + r] = wv;
  }
  __syncthreads();   // wv32 + full tile visible before phase 2

  // ---- phase 2: mol[k][d] over all t; wave owns k=3w..3w+2 ----------------
  const int kb = w * 3;
  float4 m0 = make_float4(0.f, 0.f, 0.f, 0.f), m1 = m0, m2 = m0;
#pragma unroll
  for (int tc = 0; tc < 16; ++tc) {
    const float4 wv0 = *(const float4*)&wv32[(kb + 0) * 64 + (tc << 2)];
    const float4 wv1 = *(const float4*)&wv32[(kb + 1) * 64 + (tc << 2)];
    const float4 wv2 = *(const float4*)&wv32[(kb + 2) * 64 + (tc << 2)];
    const float w0a[4] = {wv0.x, wv0.y, wv0.z, wv0.w};
    const float w1a[4] = {wv1.x, wv1.y, wv1.z, wv1.w};
    const float w2a[4] = {wv2.x, wv2.y, wv2.z, wv2.w};
#pragma unroll
    for (int j = 0; j < 4; ++j) {
      const int t = (tc << 2) + j;
      const unsigned off = t * 128 + (((lane >> 1) ^ (t & 15)) << 2) + (lane & 1) * 2;
      const uint2 pw = *(const uint2*)&tile[off];
      const float f0 = lo16(pw.x), f1 = hi16(pw.x);
      const float f2 = lo16(pw.y), f3 = hi16(pw.y);
      m0.x = fmaf(w0a[j], f0, m0.x); m0.y = fmaf(w0a[j], f1, m0.y);
      m0.z = fmaf(w0a[j], f2, m0.z); m0.w = fmaf(w0a[j], f3, m0.w);
      m1.x = fmaf(w1a[j], f0, m1.x); m1.y = fmaf(w1a[j], f1, m1.y);
      m1.z = fmaf(w1a[j], f2, m1.z); m1.w = fmaf(w1a[j], f3, m1.w);
      m2.x = fmaf(w2a[j], f0, m2.x); m2.y = fmaf(w2a[j], f1, m2.y);
      m2.z = fmaf(w2a[j], f2, m2.z); m2.w = fmaf(w2a[j], f3, m2.w);
    }
  }
  unsigned* mpb = molb + ((size_t)kb * B_N + b) * 128 + (lane << 1);
  *(uint2*)(mpb)                         = make_uint2(pk2(m0.x, m0.y), pk2(m0.z, m0.w));
  *(uint2*)(mpb + (size_t)B_N * 128)     = make_uint2(pk2(m1.x, m1.y), pk2(m1.z, m1.w));
  *(uint2*)(mpb + (size_t)2 * B_N * 128) = make_uint2(pk2(m2.x, m2.y), pk2(m2.z, m2.w));

  if (tid < 192) {
    const float4 v = *(const float4*)&wv32[tid * 4];
    const int kk = tid >> 4, t0 = (tid & 15) * 4;
    *(float4*)&out_atom[((size_t)kk * B_N + b) * T_N + t0] = v;
  }
}

// ---------------------------------------------------------------------------
// MFMA GEMM layer (unchanged from R9).
// ---------------------------------------------------------------------------
template <int S, bool AFFINE>
__global__ __launch_bounds__(256) void gemm_mfma(
    const unsigned* __restrict__ Abf, const unsigned* __restrict__ wpack,
    const float* __restrict__ bias, const float* __restrict__ alpha,
    const float* __restrict__ beta, unsigned short* __restrict__ Hout,
    float* __restrict__ ssum, float* __restrict__ ssq)
{
  __shared__ unsigned tile[64 * S * 16];
  __shared__ float redS[4][8][16];
  __shared__ float redQ[4][8][16];

  const int k   = blockIdx.y;
  const int b0  = blockIdx.x << 6;
  const int tid = threadIdx.x;
  const int lane = tid & 63;
  const int wv  = tid >> 6;
  const int ln15 = lane & 15;
  const int hq   = lane >> 4;

  {
    const int row = tid >> 2, q = tid & 3;
    const uint4* Ar = (const uint4*)Abf + ((size_t)k * B_N + b0 + row) * (S * 4) + q * S;
#pragma unroll
    for (int gi = 0; gi < S; ++gi) {
      const int g = q * S + gi;
      uint4 u = Ar[gi];
      if (AFFINE) {
        const float4 al0 = *(const float4*)(alpha + k * H_N + g * 8);
        const float4 al1 = *(const float4*)(alpha + k * H_N + g * 8 + 4);
        const float4 bt0 = *(const float4*)(beta  + k * H_N + g * 8);
        const float4 bt1 = *(const float4*)(beta  + k * H_N + g * 8 + 4);
        u.x = pk2(fmaf(lo16(u.x), al0.x, bt0.x), fmaf(hi16(u.x), al0.y, bt0.y));
        u.y = pk2(fmaf(lo16(u.y), al0.z, bt0.z), fmaf(hi16(u.y), al0.w, bt0.w));
        u.z = pk2(fmaf(lo16(u.z), al1.x, bt1.x), fmaf(hi16(u.z), al1.y, bt1.y));
        u.w = pk2(fmaf(lo16(u.w), al1.z, bt1.z), fmaf(hi16(u.w), al1.w, bt1.w));
      }
      *(uint4*)&tile[row * (S * 16) + ((g ^ (row & 15)) << 2)] = u;
    }
  }
  __syncthreads();

  const short8* wp8 = (const short8*)wpack + (size_t)k * 8 * S * 64 + lane;
  f32x4 acc[8];
#pragma unroll
  for (int nt = 0; nt < 8; ++nt) acc[nt] = (f32x4){0.f, 0.f, 0.f, 0.f};

  short8 bs0[8], bs1[8];
#pragma unroll
  for (int nt = 0; nt < 8; ++nt) bs0[nt] = wp8[(nt * S) * 64];
#pragma unroll
  for (int s = 0; s < S; ++s) {
    if (s + 1 < S) {
#pragma unroll
      for (int nt = 0; nt < 8; ++nt) {
        if (s & 1) bs0[nt] = wp8[(nt * S + s + 1) * 64];
        else       bs1[nt] = wp8[(nt * S + s + 1) * 64];
      }
    }
    const int arow = (wv << 4) + ln15;
    const unsigned aoff = arow * (S * 16) + (((4 * s + hq) ^ ln15) << 2);
    const short8 af = *(const short8*)&tile[aoff];
#pragma unroll
    for (int nt = 0; nt < 8; ++nt) {
      const short8 bf = (s & 1) ? bs1[nt] : bs0[nt];
      acc[nt] = __builtin_amdgcn_mfma_f32_16x16x32_bf16(af, bf, acc[nt], 0, 0, 0);
    }
  }

#pragma unroll
  for (int nt = 0; nt < 8; ++nt) {
    const int col = nt * 16 + ln15;
    const float bv = bias[k * H_N + col];
    float cs = 0.f, cq = 0.f;
#pragma unroll
    for (int r = 0; r < 4; ++r) {
      const float o = fmaxf(acc[nt][r] + bv, 0.f);
      cs += o; cq = fmaf(o, o, cq);
      const int row = b0 + (wv << 4) + (hq << 2) + r;
      Hout[((size_t)k * B_N + row) * H_N + col] = (unsigned short)bf16_rne(o);
    }
    cs += __shfl_xor(cs, 16); cs += __shfl_xor(cs, 32);
    cq += __shfl_xor(cq, 16); cq += __shfl_xor(cq, 32);
    if (lane < 16) { redS[wv][nt][ln15] = cs; redQ[wv][nt][ln15] = cq; }
  }
  __syncthreads();
  if (tid < 128) {
    const int nt = tid >> 4, c = tid & 15;
    float s = 0.f, q = 0.f;
#pragma unroll
    for (int i = 0; i < 4; ++i) { s += redS[i][nt][c]; q += redQ[i][nt][c]; }
    atomicAdd(&ssum[k * H_N + nt * 16 + c], s);
    atomicAdd(&ssq[k * H_N + nt * 16 + c], q);
  }
}

// stats -> alpha/beta
__global__ void bn_coef(const float* __restrict__ ssum, const float* __restrict__ ssq,
                        const float* __restrict__ g, const float* __restrict__ be,
                        float* __restrict__ alpha, float* __restrict__ beta)
{
  const int i = blockIdx.x * 256 + threadIdx.x;
  if (i >= K_N * H_N) return;
  const float inv_n = 1.f / (float)B_N;
  const float m = ssum[i] * inv_n;
  float v = fmaf(ssq[i], inv_n, -m * m);
  v = fmaxf(v, 0.f);
  const float a = g[i] * rsqrtf(v + 1e-5f);
  alpha[i] = a;
  beta[i]  = fmaf(-m, a, be[i]);
}

// final: pred[b,k] = dot(h3*al+bt, Wout) + bout  (one wave per (b,k); h3 bf16)
__global__ __launch_bounds__(256) void k_pred(
    const unsigned* __restrict__ h3, const float* __restrict__ alpha,
    const float* __restrict__ beta, const float* __restrict__ Wout,
    const float* __restrict__ bout, float* __restrict__ out)
{
  const int lane = threadIdx.x & 63;
  const int wv   = threadIdx.x >> 6;
  const int pair = blockIdx.x * 4 + wv;
  const int b = pair / K_N, k = pair - b * K_N;
  const unsigned xp = h3[((size_t)k * B_N + b) * 64 + lane];
  const float2 al = *(const float2*)(alpha + k * H_N + (lane << 1));
  const float2 be = *(const float2*)(beta  + k * H_N + (lane << 1));
  const float2 wo = *(const float2*)(Wout  + k * H_N + (lane << 1));
  float s = fmaf(lo16(xp), al.x, be.x) * wo.x + fmaf(hi16(xp), al.y, be.y) * wo.y;
#pragma unroll
  for (int off = 32; off; off >>= 1) s += __shfl_down(s, off);
  if (lane == 0) out[pair] = s + bout[k];
}

extern "C" void kernel_launch(void* const* d_in, const int* in_sizes, int n_in,
                              void* d_out, int out_size, void* d_ws, size_t ws_size,
                              hipStream_t stream)
{
  (void)in_sizes; (void)n_in; (void)out_size; (void)ws_size;
  const int*   dx     = (const int*)d_in[0];
  const float* feats  = (const float*)d_in[1];
  const float* w_atom = (const float*)d_in[2];
  const float* b_atom = (const float*)d_in[3];
  const float* W1 = (const float*)d_in[4];
  const float* b1 = (const float*)d_in[5];
  const float* g1 = (const float*)d_in[6];
  const float* be1 = (const float*)d_in[7];
  const float* W2 = (const float*)d_in[8];
  const float* b2 = (const float*)d_in[9];
  const float* g2 = (const float*)d_in[10];
  const float* be2 = (const float*)d_in[11];
  const float* W3 = (const float*)d_in[12];
  const float* b3 = (const float*)d_in[13];
  const float* g3 = (const float*)d_in[14];
  const float* be3 = (const float*)d_in[15];
  const float* Wout = (const float*)d_in[16];
  const float* bout = (const float*)d_in[17];

  float* out      = (float*)d_out;
  float* pred_out = out;                       // (B, K)
  float* atom_out = out + (size_t)B_N * K_N;   // (K, B, T)

  // ---- workspace layout (bytes) ----
  char* wsb = (char*)d_ws;
  unsigned*       molb = (unsigned*)wsb;                       // bf16 K*B*D
  unsigned short* h1   = (unsigned short*)(wsb + 25165824);
  unsigned short* h2   = (unsigned short*)(wsb + 37748736);
  unsigned short* h3   = (unsigned short*)(wsb + 50331648);
  float* st = (float*)(wsb + 62914560);
  float* s1 = st,        *q1 = st + 1536;
  float* s2 = st + 3072, *q2 = st + 4608;
  float* s3 = st + 6144, *q3 = st + 7680;
  float* ab = st + 9216;
  float* al1 = ab,        *bt1 = ab + 1536;
  float* al2 = ab + 3072, *bt2 = ab + 4608;
  float* al3 = ab + 6144, *bt3 = ab + 7680;
  unsigned* wa_frag = (unsigned*)(ab + 9216);
  unsigned* w1p = wa_frag + 2048;
  unsigned* w2p = w1p + 196608;
  unsigned* w3p = w2p + 98304;

  hipMemsetAsync(st, 0, 6 * 1536 * sizeof(float), stream);

  prep_wa<<<8, 64, 0, stream>>>(w_atom, wa_frag);
  prep_w<<<(K_N * 8 * 8 * 64 + 255) / 256, 256, 0, stream>>>(W1, w1p, 8);
  prep_w<<<(K_N * 8 * 4 * 64 + 255) / 256, 256, 0, stream>>>(W2, w2p, 4);
  prep_w<<<(K_N * 8 * 4 * 64 + 255) / 256, 256, 0, stream>>>(W3, w3p, 4);

  k1_mol<<<B_N, 256, 0, stream>>>(dx, feats, wa_frag, b_atom, atom_out, molb);

  gemm_mfma<8, false><<<dim3(64, 12), 256, 0, stream>>>(
      molb, w1p, b1, nullptr, nullptr, h1, s1, q1);
  bn_coef<<<6, 256, 0, stream>>>(s1, q1, g1, be1, al1, bt1);
  gemm_mfma<4, true><<<dim3(64, 12), 256, 0, stream>>>(
      (const unsigned*)h1, w2p, b2, al1, bt1, h2, s2, q2);
  bn_coef<<<6, 256, 0, stream>>>(s2, q2, g2, be2, al2, bt2);
  gemm_mfma<4, true><<<dim3(64, 12), 256, 0, stream>>>(
      (const unsigned*)h2, w3p, b3, al2, bt2, h3, s3, q3);
  bn_coef<<<6, 256, 0, stream>>>(s3, q3, g3, be3, al3, bt3);
  k_pred<<<B_N * K_N / 4, 256, 0, stream>>>(
      (const unsigned*)h3, al3, bt3, Wout, bout, pred_out);
}

// Round 13
// 123.940 us; speedup vs baseline: 1.5080x; 1.1735x over previous
//
#include <hip/hip_runtime.h>
#include <hip/hip_bf16.h>

#define B_N 4096
#define T_N 64
#define D_N 256
#define H_N 128
#define K_N 12

typedef __attribute__((ext_vector_type(8))) short short8;
typedef __attribute__((ext_vector_type(4))) float f32x4;

static __device__ __forceinline__ unsigned bf16_rne(float x) {
  unsigned u = __float_as_uint(x);
  return (u + 0x7fffu + ((u >> 16) & 1u)) >> 16;
}
static __device__ __forceinline__ unsigned pk2(float a, float b) {
  return bf16_rne(a) | (bf16_rne(b) << 16);
}
static __device__ __forceinline__ float lo16(unsigned u) { return __uint_as_float(u << 16); }
static __device__ __forceinline__ float hi16(unsigned u) { return __uint_as_float(u & 0xffff0000u); }

// ---------------------------------------------------------------------------
// prep_all: ONE kernel replacing prep_wa + 3x prep_w + stats memset.
// Block ranges: [0,2) wa_frag | [2,194) w1p(S=8) | [194,290) w2p(S=4) |
// [290,386) w3p(S=4) | [386,422) zero stats (9216 floats).
// ---------------------------------------------------------------------------
__device__ __forceinline__ void pack_w(const float* W, unsigned* out, int S, int id) {
  const int lane = id & 63;
  const int s  = (id >> 6) % S;
  const int nt = ((id >> 6) / S) & 7;
  const int kk = id / (64 * S * 8);
  const int n  = nt * 16 + (lane & 15);
  const int d0 = 32 * s + 8 * (lane >> 4);
  const int D  = 32 * S;
  unsigned o[4];
#pragma unroll
  for (int j = 0; j < 4; ++j) {
    const float a = W[(size_t)kk * D * H_N + (d0 + 2 * j) * H_N + n];
    const float b = W[(size_t)kk * D * H_N + (d0 + 2 * j + 1) * H_N + n];
    o[j] = pk2(a, b);
  }
  *(uint4*)(out + (size_t)id * 4) = make_uint4(o[0], o[1], o[2], o[3]);
}

__global__ void prep_all(const float* __restrict__ w_atom,
                         const float* __restrict__ W1, const float* __restrict__ W2,
                         const float* __restrict__ W3,
                         unsigned* __restrict__ wa_frag, unsigned* __restrict__ w1p,
                         unsigned* __restrict__ w2p, unsigned* __restrict__ w3p,
                         float* __restrict__ st)
{
  const int bid = blockIdx.x, tid = threadIdx.x;
  if (bid < 2) {
    const int id = bid * 256 + tid;          // [0,512)
    const int s = id >> 6, l = id & 63;
    const int k = l & 15, h = l >> 4, d0 = s * 32 + h * 8;
    unsigned o[4];
#pragma unroll
    for (int j = 0; j < 4; ++j) {
      const float a = (k < K_N) ? w_atom[k * D_N + d0 + 2 * j]     : 0.f;
      const float b = (k < K_N) ? w_atom[k * D_N + d0 + 2 * j + 1] : 0.f;
      o[j] = pk2(a, b);
    }
    *(uint4*)(wa_frag + (size_t)id * 4) = make_uint4(o[0], o[1], o[2], o[3]);
  } else if (bid < 194) {
    pack_w(W1, w1p, 8, (bid - 2) * 256 + tid);
  } else if (bid < 290) {
    pack_w(W2, w2p, 4, (bid - 194) * 256 + tid);
  } else if (bid < 386) {
    pack_w(W3, w3p, 4, (bid - 290) * 256 + tid);
  } else {
    const int id = (bid - 386) * 256 + tid;
    if (id < 9216) st[id] = 0.f;
  }
}

// ---------------------------------------------------------------------------
// K1 (unchanged from R12 / best): one block per b, 4 waves, no stage barrier.
// ---------------------------------------------------------------------------
__global__ __launch_bounds__(256, 4) void k1_mol(
    const int* __restrict__ dx, const float* __restrict__ feats,
    const unsigned* __restrict__ wa_frag, const float* __restrict__ b_atom,
    float* __restrict__ out_atom, unsigned* __restrict__ molb)
{
  __shared__ unsigned tile[64 * 128];   // 32 KB bf16 tile, 16B-granule swizzle
  __shared__ float wv32[K_N * 64];

  const int tid  = threadIdx.x;
  const int lane = tid & 63;
  const int w    = tid >> 6;
  const int b    = blockIdx.x;
  const int k    = lane & 15;
  const int h    = lane >> 4;

  short8 bfr[8];
  {
    const short8* wf8 = (const short8*)wa_frag;
#pragma unroll
    for (int s = 0; s < 8; ++s) bfr[s] = wf8[s * 64 + lane];
  }
  const float ba = (k < K_N) ? b_atom[k] : 0.f;
  const int4 dvv = *(const int4*)(dx + b * T_N + 16 * w + 4 * h);

  const float* fg = feats + ((size_t)b * 65 + 1) * 256;
#pragma unroll
  for (int c = 0; c < 4; ++c) {
    float4 v[4];
#pragma unroll
    for (int i = 0; i < 4; ++i)
      v[i] = *(const float4*)(fg + (size_t)(16 * w + 4 * c + i) * 256 + 4 * lane);
#pragma unroll
    for (int i = 0; i < 4; ++i) {
      const int tl = 4 * c + i;
      const int t  = 16 * w + tl;
      const unsigned off = t * 128 + (((lane >> 1) ^ tl) << 2) + (lane & 1) * 2;
      *(uint2*)&tile[off] = make_uint2(pk2(v[i].x, v[i].y), pk2(v[i].z, v[i].w));
    }
  }
  // No barrier: phase 1 reads only this wave's rows (lgkmcnt ordering).

  f32x4 cacc = {0.f, 0.f, 0.f, 0.f};
#pragma unroll
  for (int s = 0; s < 8; ++s) {
    const unsigned off = (16 * w + k) * 128 + (((4 * s + h) ^ k) << 2);
    const short8 afrag = *(const short8*)&tile[off];
    cacc = __builtin_amdgcn_mfma_f32_16x16x32_bf16(afrag, bfr[s], cacc, 0, 0, 0);
  }

#pragma unroll
  for (int r = 0; r < 4; ++r) {
    const float valid = (((const int*)&dvv)[r] != 0) ? 1.f : 0.f;
    const float wv = valid / (1.f + __expf(-(cacc[r] + ba)));
    if (k < K_N) wv32[k * 64 + 16 * w + 4 * h + r] = wv;
  }
  __syncthreads();   // wv32 + full tile visible before phase 2

  const int kb = w * 3;
  float4 m0 = make_float4(0.f, 0.f, 0.f, 0.f), m1 = m0, m2 = m0;
#pragma unroll
  for (int tc = 0; tc < 16; ++tc) {
    const float4 wv0 = *(const float4*)&wv32[(kb + 0) * 64 + (tc << 2)];
    const float4 wv1 = *(const float4*)&wv32[(kb + 1) * 64 + (tc << 2)];
    const float4 wv2 = *(const float4*)&wv32[(kb + 2) * 64 + (tc << 2)];
    const float w0a[4] = {wv0.x, wv0.y, wv0.z, wv0.w};
    const float w1a[4] = {wv1.x, wv1.y, wv1.z, wv1.w};
    const float w2a[4] = {wv2.x, wv2.y, wv2.z, wv2.w};
#pragma unroll
    for (int j = 0; j < 4; ++j) {
      const int t = (tc << 2) + j;
      const unsigned off = t * 128 + (((lane >> 1) ^ (t & 15)) << 2) + (lane & 1) * 2;
      const uint2 pw = *(const uint2*)&tile[off];
      const float f0 = lo16(pw.x), f1 = hi16(pw.x);
      const float f2 = lo16(pw.y), f3 = hi16(pw.y);
      m0.x = fmaf(w0a[j], f0, m0.x); m0.y = fmaf(w0a[j], f1, m0.y);
      m0.z = fmaf(w0a[j], f2, m0.z); m0.w = fmaf(w0a[j], f3, m0.w);
      m1.x = fmaf(w1a[j], f0, m1.x); m1.y = fmaf(w1a[j], f1, m1.y);
      m1.z = fmaf(w1a[j], f2, m1.z); m1.w = fmaf(w1a[j], f3, m1.w);
      m2.x = fmaf(w2a[j], f0, m2.x); m2.y = fmaf(w2a[j], f1, m2.y);
      m2.z = fmaf(w2a[j], f2, m2.z); m2.w = fmaf(w2a[j], f3, m2.w);
    }
  }
  unsigned* mpb = molb + ((size_t)kb * B_N + b) * 128 + (lane << 1);
  *(uint2*)(mpb)                         = make_uint2(pk2(m0.x, m0.y), pk2(m0.z, m0.w));
  *(uint2*)(mpb + (size_t)B_N * 128)     = make_uint2(pk2(m1.x, m1.y), pk2(m1.z, m1.w));
  *(uint2*)(mpb + (size_t)2 * B_N * 128) = make_uint2(pk2(m2.x, m2.y), pk2(m2.z, m2.w));

  if (tid < 192) {
    const float4 v = *(const float4*)&wv32[tid * 4];
    const int kk = tid >> 4, t0 = (tid & 15) * 4;
    *(float4*)&out_atom[((size_t)kk * B_N + b) * T_N + t0] = v;
  }
}

// ---------------------------------------------------------------------------
// MFMA GEMM layer (R9 core).  AFFINE variant derives alpha/beta IN PROLOGUE
// from the previous layer's ssum/ssq/g/be (bn_coef folded in; stats are
// complete because the previous gemm kernel has retired).
// ---------------------------------------------------------------------------
template <int S, bool AFFINE>
__global__ __launch_bounds__(256) void gemm_mfma(
    const unsigned* __restrict__ Abf, const unsigned* __restrict__ wpack,
    const float* __restrict__ bias,
    const float* __restrict__ ssum_p, const float* __restrict__ ssq_p,
    const float* __restrict__ g_p, const float* __restrict__ be_p,
    unsigned short* __restrict__ Hout,
    float* __restrict__ ssum, float* __restrict__ ssq)
{
  __shared__ unsigned tile[64 * S * 16];
  __shared__ float redS[4][8][16];
  __shared__ float redQ[4][8][16];
  __shared__ float alds[H_N], blds[H_N];

  const int k   = blockIdx.y;
  const int b0  = blockIdx.x << 6;
  const int tid = threadIdx.x;
  const int lane = tid & 63;
  const int wv  = tid >> 6;
  const int ln15 = lane & 15;
  const int hq   = lane >> 4;

  if (AFFINE) {   // folded bn_coef: per-block re-derivation for this k
    if (tid < H_N) {
      const float inv_n = 1.f / (float)B_N;
      const float m = ssum_p[k * H_N + tid] * inv_n;
      float v = fmaf(ssq_p[k * H_N + tid], inv_n, -m * m);
      v = fmaxf(v, 0.f);
      const float a = g_p[k * H_N + tid] * rsqrtf(v + 1e-5f);
      alds[tid] = a;
      blds[tid] = fmaf(-m, a, be_p[k * H_N + tid]);
    }
    __syncthreads();
  }

  {
    const int row = tid >> 2, q = tid & 3;
    const uint4* Ar = (const uint4*)Abf + ((size_t)k * B_N + b0 + row) * (S * 4) + q * S;
#pragma unroll
    for (int gi = 0; gi < S; ++gi) {
      const int g = q * S + gi;
      uint4 u = Ar[gi];
      if (AFFINE) {
        const float4 al0 = *(const float4*)(alds + g * 8);
        const float4 al1 = *(const float4*)(alds + g * 8 + 4);
        const float4 bt0 = *(const float4*)(blds + g * 8);
        const float4 bt1 = *(const float4*)(blds + g * 8 + 4);
        u.x = pk2(fmaf(lo16(u.x), al0.x, bt0.x), fmaf(hi16(u.x), al0.y, bt0.y));
        u.y = pk2(fmaf(lo16(u.y), al0.z, bt0.z), fmaf(hi16(u.y), al0.w, bt0.w));
        u.z = pk2(fmaf(lo16(u.z), al1.x, bt1.x), fmaf(hi16(u.z), al1.y, bt1.y));
        u.w = pk2(fmaf(lo16(u.w), al1.z, bt1.z), fmaf(hi16(u.w), al1.w, bt1.w));
      }
      *(uint4*)&tile[row * (S * 16) + ((g ^ (row & 15)) << 2)] = u;
    }
  }
  __syncthreads();

  const short8* wp8 = (const short8*)wpack + (size_t)k * 8 * S * 64 + lane;
  f32x4 acc[8];
#pragma unroll
  for (int nt = 0; nt < 8; ++nt) acc[nt] = (f32x4){0.f, 0.f, 0.f, 0.f};

  short8 bs0[8], bs1[8];
#pragma unroll
  for (int nt = 0; nt < 8; ++nt) bs0[nt] = wp8[(nt * S) * 64];
#pragma unroll
  for (int s = 0; s < S; ++s) {
    if (s + 1 < S) {
#pragma unroll
      for (int nt = 0; nt < 8; ++nt) {
        if (s & 1) bs0[nt] = wp8[(nt * S + s + 1) * 64];
        else       bs1[nt] = wp8[(nt * S + s + 1) * 64];
      }
    }
    const int arow = (wv << 4) + ln15;
    const unsigned aoff = arow * (S * 16) + (((4 * s + hq) ^ ln15) << 2);
    const short8 af = *(const short8*)&tile[aoff];
#pragma unroll
    for (int nt = 0; nt < 8; ++nt) {
      const short8 bf = (s & 1) ? bs1[nt] : bs0[nt];
      acc[nt] = __builtin_amdgcn_mfma_f32_16x16x32_bf16(af, bf, acc[nt], 0, 0, 0);
    }
  }

#pragma unroll
  for (int nt = 0; nt < 8; ++nt) {
    const int col = nt * 16 + ln15;
    const float bv = bias[k * H_N + col];
    float cs = 0.f, cq = 0.f;
#pragma unroll
    for (int r = 0; r < 4; ++r) {
      const float o = fmaxf(acc[nt][r] + bv, 0.f);
      cs += o; cq = fmaf(o, o, cq);
      const int row = b0 + (wv << 4) + (hq << 2) + r;
      Hout[((size_t)k * B_N + row) * H_N + col] = (unsigned short)bf16_rne(o);
    }
    cs += __shfl_xor(cs, 16); cs += __shfl_xor(cs, 32);
    cq += __shfl_xor(cq, 16); cq += __shfl_xor(cq, 32);
    if (lane < 16) { redS[wv][nt][ln15] = cs; redQ[wv][nt][ln15] = cq; }
  }
  __syncthreads();
  if (tid < 128) {
    const int nt = tid >> 4, c = tid & 15;
    float s = 0.f, q = 0.f;
#pragma unroll
    for (int i = 0; i < 4; ++i) { s += redS[i][nt][c]; q += redQ[i][nt][c]; }
    atomicAdd(&ssum[k * H_N + nt * 16 + c], s);
    atomicAdd(&ssq[k * H_N + nt * 16 + c], q);
  }
}

// ---------------------------------------------------------------------------
// k_pred with folded bn3: derives alpha/beta for its (k, 2 h's) inline from
// layer-3 stats (complete after gemm3 retires).
// ---------------------------------------------------------------------------
__global__ __launch_bounds__(256) void k_pred(
    const unsigned* __restrict__ h3,
    const float* __restrict__ s3, const float* __restrict__ q3,
    const float* __restrict__ g3, const float* __restrict__ be3,
    const float* __restrict__ Wout, const float* __restrict__ bout,
    float* __restrict__ out)
{
  const int lane = threadIdx.x & 63;
  const int wv   = threadIdx.x >> 6;
  const int pair = blockIdx.x * 4 + wv;
  const int b = pair / K_N, k = pair - b * K_N;
  const int i0 = k * H_N + (lane << 1);

  const float inv_n = 1.f / (float)B_N;
  const float2 sv = *(const float2*)(s3 + i0);
  const float2 qv = *(const float2*)(q3 + i0);
  const float2 gv = *(const float2*)(g3 + i0);
  const float2 bev = *(const float2*)(be3 + i0);
  const float mx = sv.x * inv_n, my = sv.y * inv_n;
  const float vx = fmaxf(fmaf(qv.x, inv_n, -mx * mx), 0.f);
  const float vy = fmaxf(fmaf(qv.y, inv_n, -my * my), 0.f);
  const float ax = gv.x * rsqrtf(vx + 1e-5f);
  const float ay = gv.y * rsqrtf(vy + 1e-5f);
  const float bx = fmaf(-mx, ax, bev.x);
  const float by = fmaf(-my, ay, bev.y);

  const unsigned xp = h3[((size_t)k * B_N + b) * 64 + lane];
  const float2 wo = *(const float2*)(Wout + i0);
  float s = fmaf(lo16(xp), ax, bx) * wo.x + fmaf(hi16(xp), ay, by) * wo.y;
#pragma unroll
  for (int off = 32; off; off >>= 1) s += __shfl_down(s, off);
  if (lane == 0) out[pair] = s + bout[k];
}

extern "C" void kernel_launch(void* const* d_in, const int* in_sizes, int n_in,
                              void* d_out, int out_size, void* d_ws, size_t ws_size,
                              hipStream_t stream)
{
  (void)in_sizes; (void)n_in; (void)out_size; (void)ws_size;
  const int*   dx     = (const int*)d_in[0];
  const float* feats  = (const float*)d_in[1];
  const float* w_atom = (const float*)d_in[2];
  const float* b_atom = (const float*)d_in[3];
  const float* W1 = (const float*)d_in[4];
  const float* b1 = (const float*)d_in[5];
  const float* g1 = (const float*)d_in[6];
  const float* be1 = (const float*)d_in[7];
  const float* W2 = (const float*)d_in[8];
  const float* b2 = (const float*)d_in[9];
  const float* g2 = (const float*)d_in[10];
  const float* be2 = (const float*)d_in[11];
  const float* W3 = (const float*)d_in[12];
  const float* b3 = (const float*)d_in[13];
  const float* g3 = (const float*)d_in[14];
  const float* be3 = (const float*)d_in[15];
  const float* Wout = (const float*)d_in[16];
  const float* bout = (const float*)d_in[17];

  float* out      = (float*)d_out;
  float* pred_out = out;                       // (B, K)
  float* atom_out = out + (size_t)B_N * K_N;   // (K, B, T)

  // ---- workspace layout (bytes) ----
  char* wsb = (char*)d_ws;
  unsigned*       molb = (unsigned*)wsb;                       // bf16 K*B*D
  unsigned short* h1   = (unsigned short*)(wsb + 25165824);
  unsigned short* h2   = (unsigned short*)(wsb + 37748736);
  unsigned short* h3   = (unsigned short*)(wsb + 50331648);
  float* st = (float*)(wsb + 62914560);                        // 9216 floats
  float* s1 = st,        *q1 = st + 1536;
  float* s2 = st + 3072, *q2 = st + 4608;
  float* s3 = st + 6144, *q3 = st + 7680;
  unsigned* wa_frag = (unsigned*)(st + 9216);
  unsigned* w1p = wa_frag + 2048;
  unsigned* w2p = w1p + 196608;
  unsigned* w3p = w2p + 98304;

  prep_all<<<422, 256, 0, stream>>>(w_atom, W1, W2, W3, wa_frag, w1p, w2p, w3p, st);

  k1_mol<<<B_N, 256, 0, stream>>>(dx, feats, wa_frag, b_atom, atom_out, molb);

  gemm_mfma<8, false><<<dim3(64, 12), 256, 0, stream>>>(
      molb, w1p, b1, nullptr, nullptr, nullptr, nullptr, h1, s1, q1);
  gemm_mfma<4, true><<<dim3(64, 12), 256, 0, stream>>>(
      (const unsigned*)h1, w2p, b2, s1, q1, g1, be1, h2, s2, q2);
  gemm_mfma<4, true><<<dim3(64, 12), 256, 0, stream>>>(
      (const unsigned*)h2, w3p, b3, s2, q2, g2, be2, h3, s3, q3);
  k_pred<<<B_N * K_N / 4, 256, 0, stream>>>(
      (const unsigned*)h3, s3, q3, g3, be3, Wout, bout, pred_out);
}